// Round 17
// baseline (615.233 us; speedup 1.0000x reference)
//
#include <hip/hip_runtime.h>
#include <hip/hip_bf16.h>

#define N_NODES 50000
#define NE      800000
#define NETOT   (NE + N_NODES)
#define NEG     0.2f
#define NBUCK   196      // ceil(50000/256) dst buckets
#define NSEG    64       // sub-counters per bucket (atomic-contention fix, r10-proven)
#define SEGCAP  128      // mean 63.8 + 8 sigma
#define NCTR    (NBUCK * NSEG)
#define CSG     512      // colstats grid

typedef unsigned short u16;
typedef unsigned int   u32;
typedef __attribute__((ext_vector_type(8))) short bf16x8;
typedef __attribute__((ext_vector_type(4))) float f32x4;

__device__ __forceinline__ float b2f(u16 v) {
    union { float f; u32 u; } c; c.u = ((u32)v) << 16; return c.f;
}
__device__ __forceinline__ u16 f2b(float f) {
    union { float f; u32 u; } c; c.f = f;
    u32 r = c.u + 0x7FFF + ((c.u >> 16) & 1);
    return (u16)(r >> 16);
}
__device__ __forceinline__ float ldf(const void* p, int i, int fmt) {
    return fmt ? b2f(((const u16*)p)[i]) : ((const float*)p)[i];
}

// ---- fused init: format probes + i64 probe + bcnt/ctr zero ----
__global__ void init_all(const u32* __restrict__ xw, const u32* __restrict__ w0,
                         const int* __restrict__ ei,
                         int* __restrict__ flag, int* __restrict__ bcnt) {
    int g = blockIdx.x * 256 + threadIdx.x;
    if (g < NCTR) bcnt[g] = 0;
    if (blockIdx.x == 0) {
        int wv = threadIdx.x >> 6, l = threadIdx.x & 63;
        if (wv == 0) {          // x storage format -> flag[0]; flag[1]=0; ctrs
            u32 v = xw[l * 50000 + 1];
            u32 e = (v >> 7) & 0xFF;
            unsigned long long m = __ballot(e >= 100 && e <= 140);
            if (l == 0) {
                flag[0] = (__popcll(m) >= 48) ? 1 : 0;
                flag[1] = 0; flag[8] = 0; flag[9] = 0;
            }
        } else if (wv == 1) {   // params family format -> flag[3]
            u32 v = w0[l * 128 + 1];
            u32 e = (v >> 7) & 0xFF;
            unsigned long long m = __ballot(e >= 100 && e <= 140);
            if (l == 0) flag[3] = (__popcll(m) >= 48) ? 1 : 0;
        } else if (wv == 2) {   // edge_index int64? -> flag[2]
            int v = ei[(l * 25000) | 1];
            unsigned long long nz = __ballot(v != 0);
            if (l == 0) flag[2] = (nz == 0ULL) ? 1 : 0;
        }
    }
}

// ---------------- binned CSR build (segmented counters, packed u32 pairs) -----
// pair word: ((d & 255) << 16) | s   (s < 50000 fits 16 bits; bucket = d >> 8)
__global__ void bin_a(const int* __restrict__ ei, const int* __restrict__ flag,
                      int* __restrict__ bcnt, u32* __restrict__ pairs) {
    int e = blockIdx.x * 256 + threadIdx.x;
    if (e >= NE) return;
    int f = flag[2];
    int s, d;
    if (f) { s = ei[2 * e]; d = ei[2 * (NE + e)]; }
    else   { s = ei[e];     d = ei[NE + e]; }
    int idx = (d >> 8) * NSEG + (blockIdx.x & (NSEG - 1));
    int pos = atomicAdd(&bcnt[idx], 1);
    if (pos < SEGCAP)
        pairs[(size_t)idx * SEGCAP + pos] = ((u32)(d & 255) << 16) | (u32)s;
}

// bin_b with inline bucket prefix (bucket_scan folded in)
__global__ __launch_bounds__(256) void bin_b(const u32* __restrict__ pairs,
        const int* __restrict__ bcnt,
        int* __restrict__ indptr, int* __restrict__ srcs) {
    __shared__ int cnt[256];
    __shared__ int scn[256];
    __shared__ int msh[NSEG];
    __shared__ int baseSh;
    int b = blockIdx.x, tid = threadIdx.x;
    int nb0 = b << 8;
    int nodesHere = min(256, N_NODES - nb0);
    if (tid < NSEG) msh[tid] = min(bcnt[b * NSEG + tid], SEGCAP);
    // prefix: edges in buckets < b (+ nb0 self-loops)
    int pre = 0;
    for (int i = tid; i < b * NSEG; i += 256) pre += min(bcnt[i], SEGCAP);
    scn[tid] = pre; __syncthreads();
    for (int off = 128; off > 0; off >>= 1) {
        if (tid < off) scn[tid] += scn[tid + off];
        __syncthreads();
    }
    if (tid == 0) baseSh = scn[0] + nb0;
    __syncthreads();
    int base = baseSh;
    cnt[tid] = (tid < nodesHere) ? 1 : 0;   // self loop
    __syncthreads();
    const u32* bp = pairs + (size_t)b * NSEG * SEGCAP;
    for (int t = tid; t < NSEG * SEGCAP; t += 256) {
        int seg = t >> 7, i = t & (SEGCAP - 1);
        if (i < msh[seg]) {
            int dloc = (int)(bp[t] >> 16);
            atomicAdd(&cnt[dloc], 1);
        }
    }
    __syncthreads();
    int v = cnt[tid];
    scn[tid] = v; __syncthreads();
    for (int off = 1; off < 256; off <<= 1) {
        int u = (tid >= off) ? scn[tid - off] : 0;
        __syncthreads();
        scn[tid] += u;
        __syncthreads();
    }
    int myoff = base + scn[tid] - v;        // exclusive offset
    if (tid < nodesHere) indptr[nb0 + tid] = myoff;
    if (tid == 255 && b == NBUCK - 1) indptr[N_NODES] = base + scn[255];
    __syncthreads();
    cnt[tid] = myoff;
    __syncthreads();
    if (tid < nodesHere) {
        int pos = atomicAdd(&cnt[tid], 1);
        srcs[pos] = nb0 + tid;
    }
    for (int t = tid; t < NSEG * SEGCAP; t += 256) {
        int seg = t >> 7, i = t & (SEGCAP - 1);
        if (i < msh[seg]) {
            u32 p = bp[t];
            int pos = atomicAdd(&cnt[p >> 16], 1);
            srcs[pos] = (int)(p & 0xffff);
        }
    }
}

// ------------- MFMA transform GEMM v4: 128-node tiles, grid.y=2 ---------------
#define LDP 136
#define NT  128
__global__ __launch_bounds__(256) void gemm_xf(const void* __restrict__ inp,
        const int* __restrict__ fin, const int* __restrict__ fw,
        const void* __restrict__ Wl, const void* __restrict__ bl,
        const void* __restrict__ Wr, const void* __restrict__ br,
        const float* __restrict__ nscale, const float* __restrict__ nshift,
        u16* __restrict__ XL, u16* __restrict__ XR) {
    __shared__ u16 As16[NT * LDP];    // A: [128 nodes][128 k] (reused for output)
    __shared__ u16 Bs16[128 * LDP];   // B^T: [128 j][128 k]
    __shared__ float Sc[128], Sh[128];
    int fi = fin[0], fb = fw[0];
    int by = blockIdx.y;
    const void* W  = by ? Wr : Wl;
    const void* bi = by ? br : bl;
    u16* dst       = by ? XR : XL;
    int n0 = blockIdx.x * NT;
    int tid = threadIdx.x;
    bool donorm = (nscale != nullptr);
    if (donorm) {
        if (tid < 128) { Sc[tid] = nscale[tid]; Sh[tid] = nshift[tid]; }
        __syncthreads();
    }
    // stage A [128 nodes][128 k]
    if (fi) {
        for (int t = tid; t < NT * 16; t += 256) {
            int node = t >> 4, c8 = (t & 15) << 3;
            int n = n0 + node;
            bf16x8 v = {0,0,0,0,0,0,0,0};
            if (n < N_NODES) v = *(const bf16x8*)((const u16*)inp + (size_t)n * 128 + c8);
            *(bf16x8*)&As16[node * LDP + c8] = v;
        }
    } else {
        for (int t = tid; t < NT * 32; t += 256) {
            int node = t >> 5, c4 = (t & 31) << 2;
            int n = n0 + node;
            float4 v = {0.f, 0.f, 0.f, 0.f};
            if (n < N_NODES) v = *(const float4*)((const float*)inp + (size_t)n * 128 + c4);
            if (donorm) {
                v.x = fmaxf(v.x * Sc[c4]     + Sh[c4],     0.f);
                v.y = fmaxf(v.y * Sc[c4 + 1] + Sh[c4 + 1], 0.f);
                v.z = fmaxf(v.z * Sc[c4 + 2] + Sh[c4 + 2], 0.f);
                v.w = fmaxf(v.w * Sc[c4 + 3] + Sh[c4 + 3], 0.f);
            }
            ushort4 h;
            h.x = f2b(v.x); h.y = f2b(v.y); h.z = f2b(v.z); h.w = f2b(v.w);
            *(ushort4*)&As16[node * LDP + c4] = h;
        }
    }
    // stage B^T [128 j][128 k]
    if (fb) {
        for (int t = tid; t < 128 * 16; t += 256) {
            int k = t >> 4, j8 = (t & 15) << 3;
            bf16x8 v = *(const bf16x8*)((const u16*)W + k * 128 + j8);
            #pragma unroll
            for (int q = 0; q < 8; ++q) Bs16[(j8 + q) * LDP + k] = (u16)v[q];
        }
    } else {
        for (int t = tid; t < 128 * 32; t += 256) {
            int k = t >> 5, j4 = (t & 31) << 2;
            float4 v = *(const float4*)((const float*)W + k * 128 + j4);
            Bs16[(j4 + 0) * LDP + k] = f2b(v.x);
            Bs16[(j4 + 1) * LDP + k] = f2b(v.y);
            Bs16[(j4 + 2) * LDP + k] = f2b(v.z);
            Bs16[(j4 + 3) * LDP + k] = f2b(v.w);
        }
    }
    __syncthreads();

    int wv = tid >> 6, lane = tid & 63;
    int quad = lane >> 4, r = lane & 15;
    int m0 = wv * 32;                 // wave owns node rows m0..m0+31 (2 m-tiles)
    f32x4 acc[2][8];
    #pragma unroll
    for (int mt = 0; mt < 2; ++mt)
        #pragma unroll
        for (int jt = 0; jt < 8; ++jt) acc[mt][jt] = (f32x4){0.f, 0.f, 0.f, 0.f};
    #pragma unroll
    for (int ks = 0; ks < 4; ++ks) {
        int ko = ks * 32 + quad * 8;
        bf16x8 af0 = *(const bf16x8*)&As16[(m0 + r) * LDP + ko];
        bf16x8 af1 = *(const bf16x8*)&As16[(m0 + 16 + r) * LDP + ko];
        #pragma unroll
        for (int jt = 0; jt < 8; ++jt) {
            bf16x8 bfr = *(const bf16x8*)&Bs16[(jt * 16 + r) * LDP + ko];
            acc[0][jt] = __builtin_amdgcn_mfma_f32_16x16x32_bf16(af0, bfr, acc[0][jt], 0, 0, 0);
            acc[1][jt] = __builtin_amdgcn_mfma_f32_16x16x32_bf16(af1, bfr, acc[1][jt], 0, 0, 0);
        }
    }
    __syncthreads();   // all waves done reading As16/Bs16
    #pragma unroll
    for (int jt = 0; jt < 8; ++jt) {
        int j = jt * 16 + r;
        float bj = ldf(bi, j, fb);
        #pragma unroll
        for (int mt = 0; mt < 2; ++mt) {
            #pragma unroll
            for (int reg = 0; reg < 4; ++reg) {
                As16[(m0 + mt * 16 + quad * 4 + reg) * LDP + j] = f2b(acc[mt][jt][reg] + bj);
            }
        }
    }
    __syncthreads();
    // 128 nodes * 16 groups of 8 cols = 2048 stores; 256 threads -> 8 reps
    #pragma unroll
    for (int rep = 0; rep < 8; ++rep) {
        int idx = rep * 256 + tid;
        int node = idx >> 4, c8 = (idx & 15) << 3;
        int n = n0 + node;
        if (n < N_NODES) {
            bf16x8 v = *(const bf16x8*)&As16[node * LDP + c8];
            *(bf16x8*)(dst + (size_t)n * 128 + c8) = v;
        }
    }
}

// ------ per-dst softmax aggregation: half-wave per edge, 3x unroll (r16) ------
__global__ __launch_bounds__(64) void agg_kernel(const u16* __restrict__ XL,
        const u16* __restrict__ XR, const void* __restrict__ att,
        const int* __restrict__ fmt,
        const int* __restrict__ indptr, const int* __restrict__ srcs,
        float4* __restrict__ OUT4) {
    int lane = threadIdx.x;
    int n = blockIdx.x;
    int eh = lane >> 5, q = lane & 31;
    int fb = fmt[0];
    ushort4 xrv = *(const ushort4*)(XR + (size_t)n * 128 + q * 4);
    float xr0 = b2f(xrv.x), xr1 = b2f(xrv.y), xr2 = b2f(xrv.z), xr3 = b2f(xrv.w);
    float a0 = ldf(att, 4 * q,     fb);
    float a1 = ldf(att, 4 * q + 1, fb);
    float a2 = ldf(att, 4 * q + 2, fb);
    float a3 = ldf(att, 4 * q + 3, fb);
    int beg = indptr[n], end = indptr[n + 1];
    float acc0 = 0.f, acc1 = 0.f, acc2 = 0.f, acc3 = 0.f, dsum = 0.f;
    int nit = (end - beg + 5) / 6;
    for (int it = 0; it < nit; ++it) {
        int iA = beg + 6 * it + eh;
        int iB = iA + 2;
        int iC = iA + 4;
        bool vA = (iA < end), vB = (iB < end), vC = (iC < end);
        int sA = vA ? srcs[iA] : 0;
        int sB = vB ? srcs[iB] : 0;
        int sC = vC ? srcs[iC] : 0;
        ushort4 xa = *(const ushort4*)(XL + (size_t)sA * 128 + q * 4);
        ushort4 xb = *(const ushort4*)(XL + (size_t)sB * 128 + q * 4);
        ushort4 xc = *(const ushort4*)(XL + (size_t)sC * 128 + q * 4);
        float A0 = b2f(xa.x), A1 = b2f(xa.y), A2 = b2f(xa.z), A3 = b2f(xa.w);
        float B0 = b2f(xb.x), B1 = b2f(xb.y), B2v = b2f(xb.z), B3 = b2f(xb.w);
        float C0 = b2f(xc.x), C1 = b2f(xc.y), C2 = b2f(xc.z), C3 = b2f(xc.w);
        float tA0 = A0 + xr0; tA0 = fmaxf(tA0, 0.f) + NEG * fminf(tA0, 0.f);
        float tA1 = A1 + xr1; tA1 = fmaxf(tA1, 0.f) + NEG * fminf(tA1, 0.f);
        float tA2 = A2 + xr2; tA2 = fmaxf(tA2, 0.f) + NEG * fminf(tA2, 0.f);
        float tA3 = A3 + xr3; tA3 = fmaxf(tA3, 0.f) + NEG * fminf(tA3, 0.f);
        float tB0 = B0 + xr0; tB0 = fmaxf(tB0, 0.f) + NEG * fminf(tB0, 0.f);
        float tB1 = B1 + xr1; tB1 = fmaxf(tB1, 0.f) + NEG * fminf(tB1, 0.f);
        float tB2 = B2v + xr2; tB2 = fmaxf(tB2, 0.f) + NEG * fminf(tB2, 0.f);
        float tB3 = B3 + xr3; tB3 = fmaxf(tB3, 0.f) + NEG * fminf(tB3, 0.f);
        float tC0 = C0 + xr0; tC0 = fmaxf(tC0, 0.f) + NEG * fminf(tC0, 0.f);
        float tC1 = C1 + xr1; tC1 = fmaxf(tC1, 0.f) + NEG * fminf(tC1, 0.f);
        float tC2 = C2 + xr2; tC2 = fmaxf(tC2, 0.f) + NEG * fminf(tC2, 0.f);
        float tC3 = C3 + xr3; tC3 = fmaxf(tC3, 0.f) + NEG * fminf(tC3, 0.f);
        float pA = tA0 * a0;
        pA = fmaf(tA1, a1, pA); pA = fmaf(tA2, a2, pA); pA = fmaf(tA3, a3, pA);
        float pB = tB0 * a0;
        pB = fmaf(tB1, a1, pB); pB = fmaf(tB2, a2, pB); pB = fmaf(tB3, a3, pB);
        float pC = tC0 * a0;
        pC = fmaf(tC1, a1, pC); pC = fmaf(tC2, a2, pC); pC = fmaf(tC3, a3, pC);
        pA += __shfl_xor(pA, 1);  pB += __shfl_xor(pB, 1);  pC += __shfl_xor(pC, 1);
        pA += __shfl_xor(pA, 2);  pB += __shfl_xor(pB, 2);  pC += __shfl_xor(pC, 2);
        pA += __shfl_xor(pA, 4);  pB += __shfl_xor(pB, 4);  pC += __shfl_xor(pC, 4);
        pA += __shfl_xor(pA, 8);  pB += __shfl_xor(pB, 8);  pC += __shfl_xor(pC, 8);
        float wA = vA ? __expf(fminf(pA, 60.f)) : 0.f;
        float wB = vB ? __expf(fminf(pB, 60.f)) : 0.f;
        float wC = vC ? __expf(fminf(pC, 60.f)) : 0.f;
        acc0 = fmaf(wA, A0, acc0); acc1 = fmaf(wA, A1, acc1);
        acc2 = fmaf(wA, A2, acc2); acc3 = fmaf(wA, A3, acc3);
        acc0 = fmaf(wB, B0, acc0); acc1 = fmaf(wB, B1, acc1);
        acc2 = fmaf(wB, B2v, acc2); acc3 = fmaf(wB, B3, acc3);
        acc0 = fmaf(wC, C0, acc0); acc1 = fmaf(wC, C1, acc1);
        acc2 = fmaf(wC, C2, acc2); acc3 = fmaf(wC, C3, acc3);
        dsum += wA + wB + wC;
    }
    acc0 += __shfl_xor(acc0, 32);
    acc1 += __shfl_xor(acc1, 32);
    acc2 += __shfl_xor(acc2, 32);
    acc3 += __shfl_xor(acc3, 32);
    dsum += __shfl_xor(dsum, 32);
    if (eh == 0) {
        float inv = 1.f / (dsum + 1e-16f);
        float4 o; o.x = acc0 * inv; o.y = acc1 * inv; o.z = acc2 * inv; o.w = acc3 * inv;
        OUT4[(size_t)n * 32 + q] = o;
    }
}

// ------- GraphNorm stats + finalize fused (last-block threadfence pattern) ----
__global__ __launch_bounds__(256) void colstats_fin(const float* __restrict__ OUT,
        const void* __restrict__ bias,
        const void* __restrict__ gamma, const void* __restrict__ beta,
        const void* __restrict__ msc, const int* __restrict__ fmt,
        float* __restrict__ Sp1, float* __restrict__ Sp2, int* __restrict__ ctr,
        float* __restrict__ scaleA, float* __restrict__ shiftB) {
    __shared__ float sh1[256], sh2[256];
    __shared__ int lastsh;
    int tid = threadIdx.x;
    int c = tid & 127, half = tid >> 7;
    int fb = fmt[0];
    float bf = ldf(bias, c, fb);
    float s1 = 0.f, s2 = 0.f;
    for (int r = blockIdx.x * 2 + half; r < N_NODES; r += gridDim.x * 2) {
        float t = OUT[r * 128 + c] + bf;
        s1 += t; s2 += t * t;
    }
    sh1[tid] = s1; sh2[tid] = s2; __syncthreads();
    if (tid < 128) {
        Sp1[blockIdx.x * 128 + tid] = sh1[tid] + sh1[tid + 128];
        Sp2[blockIdx.x * 128 + tid] = sh2[tid] + sh2[tid + 128];
    }
    __threadfence();         // order this thread's partial stores device-wide
    __syncthreads();
    if (tid == 0) {
        int old = atomicAdd(ctr, 1);
        lastsh = (old == (int)gridDim.x - 1) ? 1 : 0;
    }
    __syncthreads();
    if (!lastsh) return;
    __threadfence();         // acquire: see all partials
    float t1 = 0.f, t2 = 0.f;
    for (int b = half; b < (int)gridDim.x; b += 2) {
        t1 += Sp1[b * 128 + c];
        t2 += Sp2[b * 128 + c];
    }
    sh1[tid] = t1; sh2[tid] = t2; __syncthreads();
    if (tid < 128) {
        float S1 = sh1[tid] + sh1[tid + 128];
        float S2 = sh2[tid] + sh2[tid + 128];
        const float invN = 1.f / (float)N_NODES;
        float mean = S1 * invN;
        float ex2  = S2 * invN;
        float ms = ldf(msc, tid, fb);
        float var = ex2 - 2.f * ms * mean * mean + ms * ms * mean * mean;
        float rstd = rsqrtf(var + 1e-5f);
        float A = ldf(gamma, tid, fb) * rstd;
        scaleA[tid] = A;
        shiftB[tid] = ldf(beta, tid, fb) - A * (ms * mean - bf);
    }
}

// ---------------- fused MLP head with fused input norm+relu, fp32 out ---------
__global__ __launch_bounds__(256) void mlp_kernel(const float* __restrict__ H,
        const void* __restrict__ w1, const void* __restrict__ b1,
        const void* __restrict__ w2, const void* __restrict__ b2,
        const float* __restrict__ nscale, const float* __restrict__ nshift,
        const int* __restrict__ fmt,
        float* __restrict__ out) {
    __shared__ float W1s[128 * 64];
    __shared__ float W2s[128];
    __shared__ float b1s[64];
    __shared__ float Sc[128], Sh[128];
    int tid = threadIdx.x;
    int fb = fmt[0];
    if (fb) {
        for (int t = tid; t < 128 * 8; t += 256) {
            int row8 = t << 3;
            bf16x8 v = *(const bf16x8*)((const u16*)w1 + row8);
            #pragma unroll
            for (int q = 0; q < 8; ++q) W1s[row8 + q] = b2f((u16)v[q]);
        }
    } else {
        for (int t = tid; t < 128 * 64; t += 256) W1s[t] = ((const float*)w1)[t];
    }
    if (tid < 128) { W2s[tid] = ldf(w2, tid, fb); Sc[tid] = nscale[tid]; Sh[tid] = nshift[tid]; }
    if (tid < 64)  b1s[tid] = ldf(b1, tid, fb);
    __syncthreads();
    int n = blockIdx.x * 256 + tid;
    if (n >= N_NODES) return;
    float z[64];
    #pragma unroll
    for (int j = 0; j < 64; j++) z[j] = b1s[j];
    for (int kb = 0; kb < 128; kb += 16) {
        float h[16];
        #pragma unroll
        for (int t = 0; t < 4; t++) {
            float4 v = *(const float4*)&H[n * 128 + kb + t * 4];
            int c = kb + t * 4;
            h[4 * t]     = fmaxf(v.x * Sc[c]     + Sh[c],     0.f);
            h[4 * t + 1] = fmaxf(v.y * Sc[c + 1] + Sh[c + 1], 0.f);
            h[4 * t + 2] = fmaxf(v.z * Sc[c + 2] + Sh[c + 2], 0.f);
            h[4 * t + 3] = fmaxf(v.w * Sc[c + 3] + Sh[c + 3], 0.f);
        }
        #pragma unroll
        for (int i = 0; i < 16; i++) {
            float hv = h[i];
            const float* wrow = &W1s[(kb + i) * 64];
            #pragma unroll
            for (int j = 0; j < 64; j += 4) {
                const float4 w = *(const float4*)&wrow[j];
                z[j]     += hv * w.x;
                z[j + 1] += hv * w.y;
                z[j + 2] += hv * w.z;
                z[j + 3] += hv * w.w;
            }
        }
    }
    float o0 = ldf(b2, 0, fb), o1 = ldf(b2, 1, fb);
    #pragma unroll
    for (int j = 0; j < 64; j++) {
        float zr = fmaxf(z[j], 0.f);
        o0 += zr * W2s[j * 2];
        o1 += zr * W2s[j * 2 + 1];
    }
    if (o0 != o0) o0 = 12345.f;   // NaN canary
    if (o1 != o1) o1 = 12345.f;
    float2 o; o.x = o0; o.y = o1;
    ((float2*)out)[n] = o;
}

// ---------------- launch ----------------
extern "C" void kernel_launch(void* const* d_in, const int* in_sizes, int n_in,
                              void* d_out, int out_size, void* d_ws, size_t ws_size,
                              hipStream_t stream) {
    (void)in_sizes; (void)n_in; (void)out_size; (void)ws_size;
    const void* x    = d_in[0];
    const int*  ei   = (const int*)d_in[1];
    const void* Wl0  = d_in[2];
    const void* bl0  = d_in[3];
    const void* Wr0  = d_in[4];
    const void* br0  = d_in[5];
    const void* att0 = d_in[6];
    const void* bias0= d_in[7];
    const void* Wl1  = d_in[8];
    const void* bl1  = d_in[9];
    const void* Wr1  = d_in[10];
    const void* br1  = d_in[11];
    const void* att1 = d_in[12];
    const void* bias1= d_in[13];
    const void* g0   = d_in[14];
    const void* be0  = d_in[15];
    const void* ms0  = d_in[16];
    const void* g1   = d_in[17];
    const void* be1  = d_in[18];
    const void* ms1  = d_in[19];
    const void* W1   = d_in[20];
    const void* b1   = d_in[21];
    const void* W2   = d_in[22];
    const void* b2   = d_in[23];

    char* ws = (char*)d_ws;
    const size_t NF2 = (size_t)N_NODES * 128 * 2;
    const size_t NF4 = (size_t)N_NODES * 128 * 4;
    u16*   XLb = (u16*)(ws);
    u16*   XRb = (u16*)(ws + NF2);
    float* B2  = (float*)(ws + 2 * NF2);
    u32*   pairs = (u32*)B2;              // 6.4 MB, aliased (dead before agg writes B2)
    char* small = ws + 2 * NF2 + NF4;     // 51.2 MB offset
    float* scaleA = (float*)(small + 1024);
    float* shiftB = (float*)(small + 1536);
    int*   flag   = (int*)(small + 2048);  // [0]=xfmt [1]=0 [2]=i64 [3]=parfmt [8][9]=ctrs
    float* Sp1    = (float*)(small + 4096);             // CSG*128 f = 256 KB
    float* Sp2    = (float*)(small + 4096 + 262144);    // 256 KB
    int*   bcnt   = (int*)(small + 4096 + 524288);      // 12544 ints
    int*   indptr = (int*)(small + 4096 + 524288 + 50176);
    int*   srcs   = indptr + (N_NODES + 64);
    // footprint ~55.4 MB (r5 proved 55.5 works)

    const int* fX   = &flag[0];
    const int* fFP  = &flag[1];
    const int* fPar = &flag[3];

    init_all<<<(NCTR + 255) / 256, 256, 0, stream>>>((const u32*)x, (const u32*)Wl0,
                                                     ei, flag, bcnt);
    bin_a<<<(NE + 255) / 256, 256, 0, stream>>>(ei, flag, bcnt, pairs);
    bin_b<<<NBUCK, 256, 0, stream>>>(pairs, bcnt, indptr, srcs);

    dim3 ggemm((N_NODES + NT - 1) / NT, 2);

    for (int layer = 0; layer < 2; ++layer) {
        const void* Wl = layer ? Wl1 : Wl0;  const void* bl = layer ? bl1 : bl0;
        const void* Wr = layer ? Wr1 : Wr0;  const void* br = layer ? br1 : br0;
        const void* at = layer ? att1 : att0;
        const void* bi = layer ? bias1 : bias0;
        const void* gm = layer ? g1 : g0;    const void* bt = layer ? be1 : be0;
        const void* mS = layer ? ms1 : ms0;
        const void* inp = layer ? (const void*)B2 : x;
        const int* fin  = layer ? fFP : fX;
        const float* ns = layer ? scaleA : nullptr;
        const float* nh = layer ? shiftB : nullptr;

        gemm_xf<<<ggemm, 256, 0, stream>>>(inp, fin, fPar, Wl, bl, Wr, br, ns, nh,
                                           XLb, XRb);
        agg_kernel<<<N_NODES, 64, 0, stream>>>(XLb, XRb, at, fPar, indptr, srcs,
                                               (float4*)B2);
        colstats_fin<<<CSG, 256, 0, stream>>>(B2, bi, gm, bt, mS, fPar,
                                              Sp1, Sp2, &flag[8 + layer],
                                              scaleA, shiftB);
    }

    mlp_kernel<<<(N_NODES + 255) / 256, 256, 0, stream>>>(B2, W1, b1, W2, b2,
                                                          scaleA, shiftB, fPar,
                                                          (float*)d_out);
}

// Round 18
// 443.972 us; speedup vs baseline: 1.3857x; 1.3857x over previous
//
#include <hip/hip_runtime.h>
#include <hip/hip_bf16.h>

#define N_NODES 50000
#define NE      800000
#define NETOT   (NE + N_NODES)
#define NEG     0.2f
#define NBUCK   196      // ceil(50000/256) dst buckets
#define NSEG    64       // sub-counters per bucket (atomic-contention fix, r10-proven)
#define SEGCAP  128      // mean 63.8 + 8 sigma
#define NCTR    (NBUCK * NSEG)

typedef unsigned short u16;
typedef unsigned int   u32;
typedef __attribute__((ext_vector_type(8))) short bf16x8;
typedef __attribute__((ext_vector_type(4))) float f32x4;

__device__ __forceinline__ float b2f(u16 v) {
    union { float f; u32 u; } c; c.u = ((u32)v) << 16; return c.f;
}
__device__ __forceinline__ u16 f2b(float f) {
    union { float f; u32 u; } c; c.f = f;
    u32 r = c.u + 0x7FFF + ((c.u >> 16) & 1);
    return (u16)(r >> 16);
}
__device__ __forceinline__ float ldf(const void* p, int i, int fmt) {
    return fmt ? b2f(((const u16*)p)[i]) : ((const float*)p)[i];
}

// ---- fused init: format probes + i64 probe + bcnt zero ----
__global__ void init_all(const u32* __restrict__ xw, const u32* __restrict__ w0,
                         const int* __restrict__ ei,
                         int* __restrict__ flag, int* __restrict__ bcnt) {
    int g = blockIdx.x * 256 + threadIdx.x;
    if (g < NCTR) bcnt[g] = 0;
    if (blockIdx.x == 0) {
        int wv = threadIdx.x >> 6, l = threadIdx.x & 63;
        if (wv == 0) {          // x storage format -> flag[0]; flag[1]=0
            u32 v = xw[l * 50000 + 1];
            u32 e = (v >> 7) & 0xFF;
            unsigned long long m = __ballot(e >= 100 && e <= 140);
            if (l == 0) { flag[0] = (__popcll(m) >= 48) ? 1 : 0; flag[1] = 0; }
        } else if (wv == 1) {   // params family format -> flag[3]
            u32 v = w0[l * 128 + 1];
            u32 e = (v >> 7) & 0xFF;
            unsigned long long m = __ballot(e >= 100 && e <= 140);
            if (l == 0) flag[3] = (__popcll(m) >= 48) ? 1 : 0;
        } else if (wv == 2) {   // edge_index int64? -> flag[2]
            int v = ei[(l * 25000) | 1];
            unsigned long long nz = __ballot(v != 0);
            if (l == 0) flag[2] = (nz == 0ULL) ? 1 : 0;
        }
    }
}

// ---------------- binned CSR build (segmented counters, packed u32 pairs) -----
__global__ void bin_a(const int* __restrict__ ei, const int* __restrict__ flag,
                      int* __restrict__ bcnt, u32* __restrict__ pairs) {
    int e = blockIdx.x * 256 + threadIdx.x;
    if (e >= NE) return;
    int f = flag[2];
    int s, d;
    if (f) { s = ei[2 * e]; d = ei[2 * (NE + e)]; }
    else   { s = ei[e];     d = ei[NE + e]; }
    int idx = (d >> 8) * NSEG + (blockIdx.x & (NSEG - 1));
    int pos = atomicAdd(&bcnt[idx], 1);
    if (pos < SEGCAP)
        pairs[(size_t)idx * SEGCAP + pos] = ((u32)(d & 255) << 16) | (u32)s;
}

// bin_b with inline bucket prefix (r17-proven, kept)
__global__ __launch_bounds__(256) void bin_b(const u32* __restrict__ pairs,
        const int* __restrict__ bcnt,
        int* __restrict__ indptr, int* __restrict__ srcs) {
    __shared__ int cnt[256];
    __shared__ int scn[256];
    __shared__ int msh[NSEG];
    __shared__ int baseSh;
    int b = blockIdx.x, tid = threadIdx.x;
    int nb0 = b << 8;
    int nodesHere = min(256, N_NODES - nb0);
    if (tid < NSEG) msh[tid] = min(bcnt[b * NSEG + tid], SEGCAP);
    int pre = 0;
    for (int i = tid; i < b * NSEG; i += 256) pre += min(bcnt[i], SEGCAP);
    scn[tid] = pre; __syncthreads();
    for (int off = 128; off > 0; off >>= 1) {
        if (tid < off) scn[tid] += scn[tid + off];
        __syncthreads();
    }
    if (tid == 0) baseSh = scn[0] + nb0;
    __syncthreads();
    int base = baseSh;
    cnt[tid] = (tid < nodesHere) ? 1 : 0;   // self loop
    __syncthreads();
    const u32* bp = pairs + (size_t)b * NSEG * SEGCAP;
    for (int t = tid; t < NSEG * SEGCAP; t += 256) {
        int seg = t >> 7, i = t & (SEGCAP - 1);
        if (i < msh[seg]) {
            int dloc = (int)(bp[t] >> 16);
            atomicAdd(&cnt[dloc], 1);
        }
    }
    __syncthreads();
    int v = cnt[tid];
    scn[tid] = v; __syncthreads();
    for (int off = 1; off < 256; off <<= 1) {
        int u = (tid >= off) ? scn[tid - off] : 0;
        __syncthreads();
        scn[tid] += u;
        __syncthreads();
    }
    int myoff = base + scn[tid] - v;
    if (tid < nodesHere) indptr[nb0 + tid] = myoff;
    if (tid == 255 && b == NBUCK - 1) indptr[N_NODES] = base + scn[255];
    __syncthreads();
    cnt[tid] = myoff;
    __syncthreads();
    if (tid < nodesHere) {
        int pos = atomicAdd(&cnt[tid], 1);
        srcs[pos] = nb0 + tid;
    }
    for (int t = tid; t < NSEG * SEGCAP; t += 256) {
        int seg = t >> 7, i = t & (SEGCAP - 1);
        if (i < msh[seg]) {
            u32 p = bp[t];
            int pos = atomicAdd(&cnt[p >> 16], 1);
            srcs[pos] = (int)(p & 0xffff);
        }
    }
}

// ------------- MFMA transform GEMM v4: 128-node tiles (r17-kept) --------------
#define LDP 136
#define NT  128
__global__ __launch_bounds__(256) void gemm_xf(const void* __restrict__ inp,
        const int* __restrict__ fin, const int* __restrict__ fw,
        const void* __restrict__ Wl, const void* __restrict__ bl,
        const void* __restrict__ Wr, const void* __restrict__ br,
        const float* __restrict__ nscale, const float* __restrict__ nshift,
        u16* __restrict__ XL, u16* __restrict__ XR) {
    __shared__ u16 As16[NT * LDP];    // A: [128 nodes][128 k] (reused for output)
    __shared__ u16 Bs16[128 * LDP];   // B^T: [128 j][128 k]
    __shared__ float Sc[128], Sh[128];
    int fi = fin[0], fb = fw[0];
    int by = blockIdx.y;
    const void* W  = by ? Wr : Wl;
    const void* bi = by ? br : bl;
    u16* dst       = by ? XR : XL;
    int n0 = blockIdx.x * NT;
    int tid = threadIdx.x;
    bool donorm = (nscale != nullptr);
    if (donorm) {
        if (tid < 128) { Sc[tid] = nscale[tid]; Sh[tid] = nshift[tid]; }
        __syncthreads();
    }
    if (fi) {
        for (int t = tid; t < NT * 16; t += 256) {
            int node = t >> 4, c8 = (t & 15) << 3;
            int n = n0 + node;
            bf16x8 v = {0,0,0,0,0,0,0,0};
            if (n < N_NODES) v = *(const bf16x8*)((const u16*)inp + (size_t)n * 128 + c8);
            *(bf16x8*)&As16[node * LDP + c8] = v;
        }
    } else {
        for (int t = tid; t < NT * 32; t += 256) {
            int node = t >> 5, c4 = (t & 31) << 2;
            int n = n0 + node;
            float4 v = {0.f, 0.f, 0.f, 0.f};
            if (n < N_NODES) v = *(const float4*)((const float*)inp + (size_t)n * 128 + c4);
            if (donorm) {
                v.x = fmaxf(v.x * Sc[c4]     + Sh[c4],     0.f);
                v.y = fmaxf(v.y * Sc[c4 + 1] + Sh[c4 + 1], 0.f);
                v.z = fmaxf(v.z * Sc[c4 + 2] + Sh[c4 + 2], 0.f);
                v.w = fmaxf(v.w * Sc[c4 + 3] + Sh[c4 + 3], 0.f);
            }
            ushort4 h;
            h.x = f2b(v.x); h.y = f2b(v.y); h.z = f2b(v.z); h.w = f2b(v.w);
            *(ushort4*)&As16[node * LDP + c4] = h;
        }
    }
    if (fb) {
        for (int t = tid; t < 128 * 16; t += 256) {
            int k = t >> 4, j8 = (t & 15) << 3;
            bf16x8 v = *(const bf16x8*)((const u16*)W + k * 128 + j8);
            #pragma unroll
            for (int q = 0; q < 8; ++q) Bs16[(j8 + q) * LDP + k] = (u16)v[q];
        }
    } else {
        for (int t = tid; t < 128 * 32; t += 256) {
            int k = t >> 5, j4 = (t & 31) << 2;
            float4 v = *(const float4*)((const float*)W + k * 128 + j4);
            Bs16[(j4 + 0) * LDP + k] = f2b(v.x);
            Bs16[(j4 + 1) * LDP + k] = f2b(v.y);
            Bs16[(j4 + 2) * LDP + k] = f2b(v.z);
            Bs16[(j4 + 3) * LDP + k] = f2b(v.w);
        }
    }
    __syncthreads();

    int wv = tid >> 6, lane = tid & 63;
    int quad = lane >> 4, r = lane & 15;
    int m0 = wv * 32;                 // wave owns node rows m0..m0+31 (2 m-tiles)
    f32x4 acc[2][8];
    #pragma unroll
    for (int mt = 0; mt < 2; ++mt)
        #pragma unroll
        for (int jt = 0; jt < 8; ++jt) acc[mt][jt] = (f32x4){0.f, 0.f, 0.f, 0.f};
    #pragma unroll
    for (int ks = 0; ks < 4; ++ks) {
        int ko = ks * 32 + quad * 8;
        bf16x8 af0 = *(const bf16x8*)&As16[(m0 + r) * LDP + ko];
        bf16x8 af1 = *(const bf16x8*)&As16[(m0 + 16 + r) * LDP + ko];
        #pragma unroll
        for (int jt = 0; jt < 8; ++jt) {
            bf16x8 bfr = *(const bf16x8*)&Bs16[(jt * 16 + r) * LDP + ko];
            acc[0][jt] = __builtin_amdgcn_mfma_f32_16x16x32_bf16(af0, bfr, acc[0][jt], 0, 0, 0);
            acc[1][jt] = __builtin_amdgcn_mfma_f32_16x16x32_bf16(af1, bfr, acc[1][jt], 0, 0, 0);
        }
    }
    __syncthreads();
    #pragma unroll
    for (int jt = 0; jt < 8; ++jt) {
        int j = jt * 16 + r;
        float bj = ldf(bi, j, fb);
        #pragma unroll
        for (int mt = 0; mt < 2; ++mt) {
            #pragma unroll
            for (int reg = 0; reg < 4; ++reg) {
                As16[(m0 + mt * 16 + quad * 4 + reg) * LDP + j] = f2b(acc[mt][jt][reg] + bj);
            }
        }
    }
    __syncthreads();
    #pragma unroll
    for (int rep = 0; rep < 8; ++rep) {
        int idx = rep * 256 + tid;
        int node = idx >> 4, c8 = (idx & 15) << 3;
        int n = n0 + node;
        if (n < N_NODES) {
            bf16x8 v = *(const bf16x8*)&As16[node * LDP + c8];
            *(bf16x8*)(dst + (size_t)n * 128 + c8) = v;
        }
    }
}

// ------ per-dst softmax aggregation: half-wave per edge, 3x unroll (r16) ------
__global__ __launch_bounds__(64) void agg_kernel(const u16* __restrict__ XL,
        const u16* __restrict__ XR, const void* __restrict__ att,
        const int* __restrict__ fmt,
        const int* __restrict__ indptr, const int* __restrict__ srcs,
        float4* __restrict__ OUT4) {
    int lane = threadIdx.x;
    int n = blockIdx.x;
    int eh = lane >> 5, q = lane & 31;
    int fb = fmt[0];
    ushort4 xrv = *(const ushort4*)(XR + (size_t)n * 128 + q * 4);
    float xr0 = b2f(xrv.x), xr1 = b2f(xrv.y), xr2 = b2f(xrv.z), xr3 = b2f(xrv.w);
    float a0 = ldf(att, 4 * q,     fb);
    float a1 = ldf(att, 4 * q + 1, fb);
    float a2 = ldf(att, 4 * q + 2, fb);
    float a3 = ldf(att, 4 * q + 3, fb);
    int beg = indptr[n], end = indptr[n + 1];
    float acc0 = 0.f, acc1 = 0.f, acc2 = 0.f, acc3 = 0.f, dsum = 0.f;
    int nit = (end - beg + 5) / 6;
    for (int it = 0; it < nit; ++it) {
        int iA = beg + 6 * it + eh;
        int iB = iA + 2;
        int iC = iA + 4;
        bool vA = (iA < end), vB = (iB < end), vC = (iC < end);
        int sA = vA ? srcs[iA] : 0;
        int sB = vB ? srcs[iB] : 0;
        int sC = vC ? srcs[iC] : 0;
        ushort4 xa = *(const ushort4*)(XL + (size_t)sA * 128 + q * 4);
        ushort4 xb = *(const ushort4*)(XL + (size_t)sB * 128 + q * 4);
        ushort4 xc = *(const ushort4*)(XL + (size_t)sC * 128 + q * 4);
        float A0 = b2f(xa.x), A1 = b2f(xa.y), A2 = b2f(xa.z), A3 = b2f(xa.w);
        float B0 = b2f(xb.x), B1 = b2f(xb.y), B2v = b2f(xb.z), B3 = b2f(xb.w);
        float C0 = b2f(xc.x), C1 = b2f(xc.y), C2 = b2f(xc.z), C3 = b2f(xc.w);
        float tA0 = A0 + xr0; tA0 = fmaxf(tA0, 0.f) + NEG * fminf(tA0, 0.f);
        float tA1 = A1 + xr1; tA1 = fmaxf(tA1, 0.f) + NEG * fminf(tA1, 0.f);
        float tA2 = A2 + xr2; tA2 = fmaxf(tA2, 0.f) + NEG * fminf(tA2, 0.f);
        float tA3 = A3 + xr3; tA3 = fmaxf(tA3, 0.f) + NEG * fminf(tA3, 0.f);
        float tB0 = B0 + xr0; tB0 = fmaxf(tB0, 0.f) + NEG * fminf(tB0, 0.f);
        float tB1 = B1 + xr1; tB1 = fmaxf(tB1, 0.f) + NEG * fminf(tB1, 0.f);
        float tB2 = B2v + xr2; tB2 = fmaxf(tB2, 0.f) + NEG * fminf(tB2, 0.f);
        float tB3 = B3 + xr3; tB3 = fmaxf(tB3, 0.f) + NEG * fminf(tB3, 0.f);
        float tC0 = C0 + xr0; tC0 = fmaxf(tC0, 0.f) + NEG * fminf(tC0, 0.f);
        float tC1 = C1 + xr1; tC1 = fmaxf(tC1, 0.f) + NEG * fminf(tC1, 0.f);
        float tC2 = C2 + xr2; tC2 = fmaxf(tC2, 0.f) + NEG * fminf(tC2, 0.f);
        float tC3 = C3 + xr3; tC3 = fmaxf(tC3, 0.f) + NEG * fminf(tC3, 0.f);
        float pA = tA0 * a0;
        pA = fmaf(tA1, a1, pA); pA = fmaf(tA2, a2, pA); pA = fmaf(tA3, a3, pA);
        float pB = tB0 * a0;
        pB = fmaf(tB1, a1, pB); pB = fmaf(tB2, a2, pB); pB = fmaf(tB3, a3, pB);
        float pC = tC0 * a0;
        pC = fmaf(tC1, a1, pC); pC = fmaf(tC2, a2, pC); pC = fmaf(tC3, a3, pC);
        pA += __shfl_xor(pA, 1);  pB += __shfl_xor(pB, 1);  pC += __shfl_xor(pC, 1);
        pA += __shfl_xor(pA, 2);  pB += __shfl_xor(pB, 2);  pC += __shfl_xor(pC, 2);
        pA += __shfl_xor(pA, 4);  pB += __shfl_xor(pB, 4);  pC += __shfl_xor(pC, 4);
        pA += __shfl_xor(pA, 8);  pB += __shfl_xor(pB, 8);  pC += __shfl_xor(pC, 8);
        float wA = vA ? __expf(fminf(pA, 60.f)) : 0.f;
        float wB = vB ? __expf(fminf(pB, 60.f)) : 0.f;
        float wC = vC ? __expf(fminf(pC, 60.f)) : 0.f;
        acc0 = fmaf(wA, A0, acc0); acc1 = fmaf(wA, A1, acc1);
        acc2 = fmaf(wA, A2, acc2); acc3 = fmaf(wA, A3, acc3);
        acc0 = fmaf(wB, B0, acc0); acc1 = fmaf(wB, B1, acc1);
        acc2 = fmaf(wB, B2v, acc2); acc3 = fmaf(wB, B3, acc3);
        acc0 = fmaf(wC, C0, acc0); acc1 = fmaf(wC, C1, acc1);
        acc2 = fmaf(wC, C2, acc2); acc3 = fmaf(wC, C3, acc3);
        dsum += wA + wB + wC;
    }
    acc0 += __shfl_xor(acc0, 32);
    acc1 += __shfl_xor(acc1, 32);
    acc2 += __shfl_xor(acc2, 32);
    acc3 += __shfl_xor(acc3, 32);
    dsum += __shfl_xor(dsum, 32);
    if (eh == 0) {
        float inv = 1.f / (dsum + 1e-16f);
        float4 o; o.x = acc0 * inv; o.y = acc1 * inv; o.z = acc2 * inv; o.w = acc3 * inv;
        OUT4[(size_t)n * 32 + q] = o;
    }
}

// ---------------- GraphNorm stats: per-block partials (r16-proven) ----------
__global__ __launch_bounds__(256) void colstats(const float* __restrict__ OUT,
        const void* __restrict__ bias, const int* __restrict__ fmt,
        float* __restrict__ Sp1, float* __restrict__ Sp2) {
    __shared__ float sh1[256], sh2[256];
    int tid = threadIdx.x;
    int c = tid & 127, half = tid >> 7;
    float bf = ldf(bias, c, fmt[0]);
    float s1 = 0.f, s2 = 0.f;
    for (int r = blockIdx.x * 2 + half; r < N_NODES; r += gridDim.x * 2) {
        float t = OUT[r * 128 + c] + bf;
        s1 += t; s2 += t * t;
    }
    sh1[tid] = s1; sh2[tid] = s2; __syncthreads();
    if (tid < 128) {
        Sp1[blockIdx.x * 128 + tid] = sh1[tid] + sh1[tid + 128];
        Sp2[blockIdx.x * 128 + tid] = sh2[tid] + sh2[tid + 128];
    }
}

// parallel finalize: 128 blocks (one per channel), 256 threads reduce 256 partials
__global__ __launch_bounds__(256) void finalize_norm(const float* __restrict__ Sp1,
        const float* __restrict__ Sp2,
        const void* __restrict__ gamma, const void* __restrict__ beta,
        const void* __restrict__ msc, const void* __restrict__ bias,
        const int* __restrict__ fmt,
        float* __restrict__ scaleA, float* __restrict__ shiftB) {
    __shared__ float sh1[256], sh2[256];
    int c = blockIdx.x, tid = threadIdx.x;
    sh1[tid] = Sp1[tid * 128 + c];
    sh2[tid] = Sp2[tid * 128 + c];
    __syncthreads();
    for (int off = 128; off > 0; off >>= 1) {
        if (tid < off) { sh1[tid] += sh1[tid + off]; sh2[tid] += sh2[tid + off]; }
        __syncthreads();
    }
    if (tid == 0) {
        int fb = fmt[0];
        const float invN = 1.f / (float)N_NODES;
        float mean = sh1[0] * invN;
        float ex2  = sh2[0] * invN;
        float ms = ldf(msc, c, fb);
        float var = ex2 - 2.f * ms * mean * mean + ms * ms * mean * mean;
        float rstd = rsqrtf(var + 1e-5f);
        float A = ldf(gamma, c, fb) * rstd;
        scaleA[c] = A;
        shiftB[c] = ldf(beta, c, fb) - A * (ms * mean - ldf(bias, c, fb));
    }
}

// ---------------- fused MLP head with fused input norm+relu, fp32 out ---------
__global__ __launch_bounds__(256) void mlp_kernel(const float* __restrict__ H,
        const void* __restrict__ w1, const void* __restrict__ b1,
        const void* __restrict__ w2, const void* __restrict__ b2,
        const float* __restrict__ nscale, const float* __restrict__ nshift,
        const int* __restrict__ fmt,
        float* __restrict__ out) {
    __shared__ float W1s[128 * 64];
    __shared__ float W2s[128];
    __shared__ float b1s[64];
    __shared__ float Sc[128], Sh[128];
    int tid = threadIdx.x;
    int fb = fmt[0];
    if (fb) {
        for (int t = tid; t < 128 * 8; t += 256) {
            int row8 = t << 3;
            bf16x8 v = *(const bf16x8*)((const u16*)w1 + row8);
            #pragma unroll
            for (int q = 0; q < 8; ++q) W1s[row8 + q] = b2f((u16)v[q]);
        }
    } else {
        for (int t = tid; t < 128 * 64; t += 256) W1s[t] = ((const float*)w1)[t];
    }
    if (tid < 128) { W2s[tid] = ldf(w2, tid, fb); Sc[tid] = nscale[tid]; Sh[tid] = nshift[tid]; }
    if (tid < 64)  b1s[tid] = ldf(b1, tid, fb);
    __syncthreads();
    int n = blockIdx.x * 256 + tid;
    if (n >= N_NODES) return;
    float z[64];
    #pragma unroll
    for (int j = 0; j < 64; j++) z[j] = b1s[j];
    for (int kb = 0; kb < 128; kb += 16) {
        float h[16];
        #pragma unroll
        for (int t = 0; t < 4; t++) {
            float4 v = *(const float4*)&H[n * 128 + kb + t * 4];
            int c = kb + t * 4;
            h[4 * t]     = fmaxf(v.x * Sc[c]     + Sh[c],     0.f);
            h[4 * t + 1] = fmaxf(v.y * Sc[c + 1] + Sh[c + 1], 0.f);
            h[4 * t + 2] = fmaxf(v.z * Sc[c + 2] + Sh[c + 2], 0.f);
            h[4 * t + 3] = fmaxf(v.w * Sc[c + 3] + Sh[c + 3], 0.f);
        }
        #pragma unroll
        for (int i = 0; i < 16; i++) {
            float hv = h[i];
            const float* wrow = &W1s[(kb + i) * 64];
            #pragma unroll
            for (int j = 0; j < 64; j += 4) {
                const float4 w = *(const float4*)&wrow[j];
                z[j]     += hv * w.x;
                z[j + 1] += hv * w.y;
                z[j + 2] += hv * w.z;
                z[j + 3] += hv * w.w;
            }
        }
    }
    float o0 = ldf(b2, 0, fb), o1 = ldf(b2, 1, fb);
    #pragma unroll
    for (int j = 0; j < 64; j++) {
        float zr = fmaxf(z[j], 0.f);
        o0 += zr * W2s[j * 2];
        o1 += zr * W2s[j * 2 + 1];
    }
    if (o0 != o0) o0 = 12345.f;   // NaN canary
    if (o1 != o1) o1 = 12345.f;
    float2 o; o.x = o0; o.y = o1;
    ((float2*)out)[n] = o;
}

// ---------------- launch ----------------
extern "C" void kernel_launch(void* const* d_in, const int* in_sizes, int n_in,
                              void* d_out, int out_size, void* d_ws, size_t ws_size,
                              hipStream_t stream) {
    (void)in_sizes; (void)n_in; (void)out_size; (void)ws_size;
    const void* x    = d_in[0];
    const int*  ei   = (const int*)d_in[1];
    const void* Wl0  = d_in[2];
    const void* bl0  = d_in[3];
    const void* Wr0  = d_in[4];
    const void* br0  = d_in[5];
    const void* att0 = d_in[6];
    const void* bias0= d_in[7];
    const void* Wl1  = d_in[8];
    const void* bl1  = d_in[9];
    const void* Wr1  = d_in[10];
    const void* br1  = d_in[11];
    const void* att1 = d_in[12];
    const void* bias1= d_in[13];
    const void* g0   = d_in[14];
    const void* be0  = d_in[15];
    const void* ms0  = d_in[16];
    const void* g1   = d_in[17];
    const void* be1  = d_in[18];
    const void* ms1  = d_in[19];
    const void* W1   = d_in[20];
    const void* b1   = d_in[21];
    const void* W2   = d_in[22];
    const void* b2   = d_in[23];

    char* ws = (char*)d_ws;
    const size_t NF2 = (size_t)N_NODES * 128 * 2;
    const size_t NF4 = (size_t)N_NODES * 128 * 4;
    u16*   XLb = (u16*)(ws);
    u16*   XRb = (u16*)(ws + NF2);
    float* B2  = (float*)(ws + 2 * NF2);
    u32*   pairs = (u32*)B2;              // 6.4 MB, aliased (dead before agg writes B2)
    char* small = ws + 2 * NF2 + NF4;     // 51.2 MB offset
    float* scaleA = (float*)(small + 1024);
    float* shiftB = (float*)(small + 1536);
    int*   flag   = (int*)(small + 2048);  // [0]=xfmt [1]=0 [2]=i64 [3]=parfmt
    float* Sp1    = (float*)(small + 4096);             // 256*128 f = 128 KB
    float* Sp2    = (float*)(small + 4096 + 131072);
    int*   bcnt   = (int*)(small + 4096 + 262144);      // 12544 ints
    int*   indptr = (int*)(small + 4096 + 262144 + 50176);
    int*   srcs   = indptr + (N_NODES + 64);
    // footprint ~55.1 MB (proven budget)

    const int* fX   = &flag[0];
    const int* fFP  = &flag[1];
    const int* fPar = &flag[3];

    init_all<<<(NCTR + 255) / 256, 256, 0, stream>>>((const u32*)x, (const u32*)Wl0,
                                                     ei, flag, bcnt);
    bin_a<<<(NE + 255) / 256, 256, 0, stream>>>(ei, flag, bcnt, pairs);
    bin_b<<<NBUCK, 256, 0, stream>>>(pairs, bcnt, indptr, srcs);

    dim3 ggemm((N_NODES + NT - 1) / NT, 2);

    for (int layer = 0; layer < 2; ++layer) {
        const void* Wl = layer ? Wl1 : Wl0;  const void* bl = layer ? bl1 : bl0;
        const void* Wr = layer ? Wr1 : Wr0;  const void* br = layer ? br1 : br0;
        const void* at = layer ? att1 : att0;
        const void* bi = layer ? bias1 : bias0;
        const void* gm = layer ? g1 : g0;    const void* bt = layer ? be1 : be0;
        const void* mS = layer ? ms1 : ms0;
        const void* inp = layer ? (const void*)B2 : x;
        const int* fin  = layer ? fFP : fX;
        const float* ns = layer ? scaleA : nullptr;
        const float* nh = layer ? shiftB : nullptr;

        gemm_xf<<<ggemm, 256, 0, stream>>>(inp, fin, fPar, Wl, bl, Wr, br, ns, nh,
                                           XLb, XRb);
        agg_kernel<<<N_NODES, 64, 0, stream>>>(XLb, XRb, at, fPar, indptr, srcs,
                                               (float4*)B2);
        colstats<<<256, 256, 0, stream>>>(B2, bi, fPar, Sp1, Sp2);
        finalize_norm<<<128, 256, 0, stream>>>(Sp1, Sp2, gm, bt, mS, bi, fPar,
                                               scaleA, shiftB);
    }

    mlp_kernel<<<(N_NODES + 255) / 256, 256, 0, stream>>>(B2, W1, b1, W2, b2,
                                                          scaleA, shiftB, fPar,
                                                          (float*)d_out);
}